// Round 8
// baseline (368.905 us; speedup 1.0000x reference)
//
#include <hip/hip_runtime.h>
#include <hip/hip_bf16.h>
#include <stdint.h>

// Problem constants (fixed shape): B=16, L=65536, H=64, K=64
#define LCOUNT 65536
#define LOUT   65473   // L - (H-1)
#define KF     64
#define HH     64
#define TL     512     // output positions per block (grid 2048 -> 8 blocks/CU)
#define ROW4   592     // rep row stride in shorts; (592/2) % 32 == 8 -> rows stagger bank groups

typedef __attribute__((ext_vector_type(8))) short  short8;   // 8 bf16 (4 VGPRs)
typedef __attribute__((ext_vector_type(4))) short  short4v;  // 4 bf16 (2 VGPRs, 8B align)
typedef __attribute__((ext_vector_type(4))) float  float4v;  // 4 fp32
typedef __attribute__((ext_vector_type(2))) float  float2v;  // 2 fp32

__device__ __forceinline__ unsigned short f2bf(float f) {
    union { float f; uint32_t u; } c; c.f = f;
    uint32_t u = c.u;
    u += 0x7FFFu + ((u >> 16) & 1u);   // round-to-nearest-even
    return (unsigned short)(u >> 16);
}

// 8 waves/SIMD requested -> compiler must fit VGPR <= 64 (the binary occupancy cliff).
// Hot-loop live set ~60: afrag(32) + acc(16) + b(8) + addressing. No payload batching,
// no ws/bs register hoist (LDS broadcasts are free), store straight from acc.
__global__ __launch_bounds__(256, 8)
void hankel_kernel(const float* __restrict__ x,
                   const float* __restrict__ W,
                   const float* __restrict__ bias,
                   float* __restrict__ out)
{
    // LDS: 2304 + 4736 + 4096 + 256 + 256 = 11648 B -> 8 blocks/CU = 32 waves/CU
    __shared__ __align__(16) float          xs_f[TL + 64];
    __shared__ __align__(16) unsigned short rep4[4 * ROW4];   // rep4[s][i] = bf16(x[blk + i + s])
    __shared__ __align__(16) float          muinv_s[2 * TL];  // interleaved {mu, inv}
    __shared__ float wsum_s[KF];
    __shared__ float bias_s[KF];

    const int tid  = threadIdx.x;
    const int lane = tid & 63;
    const int wv   = tid >> 6;
    const int m    = lane & 15;   // A-row (filter sub-idx) AND C/D col (position)
    const int quad = lane >> 4;

    const int tile     = blockIdx.x;
    const int bb       = blockIdx.y;
    const int block_lo = tile * TL;

    // ---- Phase A: stage x tile (float4 loads): fp32 for stats + packed bf16 row 0 ----
    {
        const float4v* xrow4 = (const float4v*)(x + (size_t)bb * LCOUNT);
        const int base4 = block_lo >> 2;           // block_lo % 4 == 0
        const int nf4   = (TL + 64) / 4;           // 144
        if (tid < nf4) {
            int g4 = base4 + tid;
            if (g4 > LCOUNT / 4 - 1) g4 = LCOUNT / 4 - 1;  // tail clamp; masked at store
            float4v v = xrow4[g4];
            *(float4v*)(xs_f + 4 * tid) = v;
            uint32_t plo = (uint32_t)f2bf(v[0]) | ((uint32_t)f2bf(v[1]) << 16);
            uint32_t phi = (uint32_t)f2bf(v[2]) | ((uint32_t)f2bf(v[3]) << 16);
            *(uint2*)(rep4 + 4 * tid) = make_uint2(plo, phi);   // row 0 (shift 0)
        }
    }

    // ---- Wsum[k] and bias -> LDS (threads 0..63; W is 16KB L1/L2-hot) ----
    if (tid < KF) {
        const float4v* wr = (const float4v*)(W + tid * HH);
        float s = 0.f;
        #pragma unroll
        for (int i = 0; i < HH / 4; ++i) {
            float4v w = wr[i];
            s += w[0] + w[1] + w[2] + w[3];
        }
        wsum_s[tid] = s;
        bias_s[tid] = bias[tid];
    }

    // ---- A fragments (W): afrag[t][ki] -> A[m=lane&15][h=quad*8+j+32*ki], filter k=t*16+m ----
    short8 afrag[4][2];
    #pragma unroll
    for (int t = 0; t < 4; ++t) {
        const int k = t * 16 + m;
        #pragma unroll
        for (int ki = 0; ki < 2; ++ki) {
            const float4v* wp = (const float4v*)(W + k * HH + quad * 8 + ki * 32);
            float4v w0 = wp[0];
            float4v w1 = wp[1];
            short8 f;
            f[0] = (short)f2bf(w0[0]); f[1] = (short)f2bf(w0[1]);
            f[2] = (short)f2bf(w0[2]); f[3] = (short)f2bf(w0[3]);
            f[4] = (short)f2bf(w1[0]); f[5] = (short)f2bf(w1[1]);
            f[6] = (short)f2bf(w1[2]); f[7] = (short)f2bf(w1[3]);
            afrag[t][ki] = f;
        }
    }

    __syncthreads();

    // ---- Phase B1: window stats: threads 0..127 own 4 consecutive positions each ----
    if (tid < TL / 4) {
        const int p0 = 4 * tid;
        const float4v* xv = (const float4v*)(xs_f + p0);   // 16B aligned
        float s1 = 0.f, s2 = 0.f;
        float4v v0 = xv[0];
        float4v v16 = xv[16];
        #pragma unroll
        for (int i = 0; i < 16; ++i) {
            float4v v = xv[i];
            s1 += v[0] + v[1] + v[2] + v[3];
            s2 += v[0] * v[0] + v[1] * v[1] + v[2] * v[2] + v[3] * v[3];
        }
        float mu4[4], inv4[4];
        #pragma unroll
        for (int i = 0; i < 4; ++i) {
            if (i > 0) {
                float xo = v0[i - 1], xn = v16[i - 1];   // slide window by 1
                s1 += xn - xo;
                s2 += xn * xn - xo * xo;
            }
            float mu  = s1 * (1.f / 64.f);
            float var = (s2 - 64.f * mu * mu) * (1.f / 63.f);
            var = var < 0.f ? 0.f : var;
            mu4[i]  = mu;
            inv4[i] = 1.f / (sqrtf(var) + 1e-6f);
        }
        float4v lo4, hi4;
        lo4[0] = mu4[0]; lo4[1] = inv4[0]; lo4[2] = mu4[1]; lo4[3] = inv4[1];
        hi4[0] = mu4[2]; hi4[1] = inv4[2]; hi4[2] = mu4[3]; hi4[3] = inv4[3];
        *(float4v*)(muinv_s + 8 * tid)     = lo4;   // byte 32*tid -> 16B aligned
        *(float4v*)(muinv_s + 8 * tid + 4) = hi4;
    }

    // ---- Phase B2: build shifted bf16 rows 1..3 from row 0 ----
    // 216 tasks: c = tid/3 in 0..71 (all 72 chunks), s = 1 + tid%3 in 1..3.
    // (R7 bug: s=tid&3,c=tid>>2 reached only c<64 -> chunks 64..71 uninitialized -> inf.)
    if (tid < 216) {
        const int c = tid / 3;           // 0..71
        const int s = 1 + tid % 3;       // 1..3
        const int i0 = 8 * c + s;        // reads row0[i0..i0+7], i0+7 <= 578 (junk >575
                                         // lands only at row_s[>=573], read ceiling is 571)
        short8 w;
        #pragma unroll
        for (int j = 0; j < 8; ++j) w[j] = (short)rep4[i0 + j];
        *(short8*)(rep4 + s * ROW4 + 8 * c) = w;   // 16B aligned
    }
    __syncthreads();

    // ---- Phase C: MFMA + direct 1KB stores ----
    // B[k=quad*8+j][n=m] = rep4[m&3][ p0 + (m&12) + quad*8 (+32ki) + j ]  (8B aligned)
    const unsigned short* myrow = rep4 + (m & 3) * ROW4 + (m & 12) + quad * 8;
    float* const outb = out + (size_t)bb * LOUT * KF + quad * 4;

    // Only the last tile can touch pos >= LOUT: block-uniform guard.
    const bool full = (block_lo + TL) <= LOUT;

    for (int g = wv; g < TL / 16; g += 4) {
        const int p0 = g * 16;

        // b64 reads, bank-verified conflict-free
        short4v a0 = *(const short4v*)(myrow + p0);
        short4v a1 = *(const short4v*)(myrow + p0 + 4);
        short4v a2 = *(const short4v*)(myrow + p0 + 32);
        short4v a3 = *(const short4v*)(myrow + p0 + 36);
        short8 b0 = __builtin_shufflevector(a0, a1, 0, 1, 2, 3, 4, 5, 6, 7);
        short8 b1 = __builtin_shufflevector(a2, a3, 0, 1, 2, 3, 4, 5, 6, 7);

        float2v mi = *(const float2v*)(muinv_s + 2 * (p0 + m));  // 4-lane broadcast
        const float invv = mi[1];
        const float nmi  = -mi[0] * invv;   // -mu*inv

        float4v acc[4];
        #pragma unroll
        for (int t = 0; t < 4; ++t) acc[t] = (float4v){0.f, 0.f, 0.f, 0.f};
        #pragma unroll
        for (int t = 0; t < 4; ++t) {
            acc[t] = __builtin_amdgcn_mfma_f32_16x16x32_bf16(afrag[t][0], b0, acc[t], 0, 0, 0);
            acc[t] = __builtin_amdgcn_mfma_f32_16x16x32_bf16(afrag[t][1], b1, acc[t], 0, 0, 0);
        }

        const int pos = block_lo + p0 + m;
        float* op = outb + (size_t)pos * KF;
        if (full | (pos < LOUT)) {
            #pragma unroll
            for (int t = 0; t < 4; ++t) {
                float4v ws = *(const float4v*)(wsum_s + t * 16 + quad * 4);  // broadcast
                float4v bs = *(const float4v*)(bias_s + t * 16 + quad * 4);  // broadcast
                float4v v;
                #pragma unroll
                for (int r = 0; r < 4; ++r) {
                    float vv = fmaf(acc[t][r], invv, fmaf(nmi, ws[r], bs[r]));
                    v[r] = vv > 0.f ? vv : 0.f;
                }
                *(float4v*)(op + t * 16) = v;   // 1KB contiguous per instruction
            }
        }
    }

    // ---- output 1: warmup scalar = 63 ----
    if (tile == 0 && bb == 0 && tid == 0) {
        out[(size_t)16 * LOUT * KF] = 63.0f;
    }
}

extern "C" void kernel_launch(void* const* d_in, const int* in_sizes, int n_in,
                              void* d_out, int out_size, void* d_ws, size_t ws_size,
                              hipStream_t stream) {
    const float* x = (const float*)d_in[0];   // (16, 65536) fp32
    const float* W = (const float*)d_in[1];   // (64, 64) fp32
    const float* b = (const float*)d_in[2];   // (64,) fp32
    float* out = (float*)d_out;               // 16*65473*64 fp32 + 1 (warmup)

    dim3 grid((LOUT + TL - 1) / TL, 16);      // 128 tiles x 16 batches = 2048 blocks
    hankel_kernel<<<grid, 256, 0, stream>>>(x, W, b, out);
}

// Round 9
// 279.915 us; speedup vs baseline: 1.3179x; 1.3179x over previous
//
#include <hip/hip_runtime.h>
#include <hip/hip_bf16.h>
#include <stdint.h>

// Problem constants (fixed shape): B=16, L=65536, H=64, K=64
#define LCOUNT 65536
#define LOUT   65473   // L - (H-1)
#define KF     64
#define HH     64
#define TL     512     // output positions per block (grid 2048 -> 8 blocks/CU)
#define ROW4   592     // rep row stride in shorts; (592/2) % 32 == 8 -> rows stagger bank groups
#define BSTRIDE 36     // bounce row stride in floats (R2/R5-measured body)

typedef __attribute__((ext_vector_type(8))) short  short8;   // 8 bf16 (4 VGPRs)
typedef __attribute__((ext_vector_type(4))) short  short4v;  // 4 bf16 (2 VGPRs, 8B align)
typedef __attribute__((ext_vector_type(4))) float  float4v;  // 4 fp32
typedef __attribute__((ext_vector_type(2))) float  float2v;  // 2 fp32

__device__ __forceinline__ unsigned short f2bf(float f) {
    union { float f; uint32_t u; } c; c.f = f;
    uint32_t u = c.u;
    u += 0x7FFFu + ((u >> 16) & 1u);   // round-to-nearest-even
    return (unsigned short)(u >> 16);
}

// Cap 128 VGPR (min 4 waves/EU); the bounce-epilogue body MEASURES at 64 VGPR (R5),
// which gives 8 waves/SIMD -> with 18.6KB LDS the occupancy limit is 8 blocks/CU.
// Do NOT force (256,8): R6/R8 showed a forced 64-cap spills other epilogues to scratch.
__global__ __launch_bounds__(256, 4)
void hankel_kernel(const float* __restrict__ x,
                   const float* __restrict__ W,
                   const float* __restrict__ bias,
                   float* __restrict__ out)
{
    // LDS: pool(9216, aliases xs_f[576]+bounce[2304]) + rep4(4736) + muinv(4096)
    //      + wsum(256) + bias(256) = 18560 B -> 8 blocks/CU = 32 waves/CU.
    // xs_f is dead after Phase B1; bounce is only touched after the 2nd barrier -> safe alias.
    __shared__ __align__(16) float          pool[4 * 16 * BSTRIDE];   // 2304 floats
    __shared__ __align__(16) unsigned short rep4[4 * ROW4];   // rep4[s][i] = bf16(x[blk + i + s])
    __shared__ __align__(16) float          muinv_s[2 * TL];  // interleaved {mu, inv}
    __shared__ float wsum_s[KF];
    __shared__ float bias_s[KF];

    float* const xs_f = pool;                 // Phase A/B1 view (576 floats)

    const int tid  = threadIdx.x;
    const int lane = tid & 63;
    const int wv   = tid >> 6;
    const int m    = lane & 15;   // A-row (filter sub-idx) AND C/D col (position)
    const int quad = lane >> 4;

    const int tile     = blockIdx.x;
    const int bb       = blockIdx.y;
    const int block_lo = tile * TL;

    // ---- Phase A: stage x tile (float4 loads): fp32 for stats + packed bf16 row 0 ----
    {
        const float4v* xrow4 = (const float4v*)(x + (size_t)bb * LCOUNT);
        const int base4 = block_lo >> 2;           // block_lo % 4 == 0
        const int nf4   = (TL + 64) / 4;           // 144
        if (tid < nf4) {
            int g4 = base4 + tid;
            if (g4 > LCOUNT / 4 - 1) g4 = LCOUNT / 4 - 1;  // tail clamp; masked at store
            float4v v = xrow4[g4];
            *(float4v*)(xs_f + 4 * tid) = v;
            uint32_t plo = (uint32_t)f2bf(v[0]) | ((uint32_t)f2bf(v[1]) << 16);
            uint32_t phi = (uint32_t)f2bf(v[2]) | ((uint32_t)f2bf(v[3]) << 16);
            *(uint2*)(rep4 + 4 * tid) = make_uint2(plo, phi);   // row 0 (shift 0)
        }
    }

    // ---- Wsum[k] and bias -> LDS (threads 0..63; W is 16KB L1/L2-hot) ----
    if (tid < KF) {
        const float4v* wr = (const float4v*)(W + tid * HH);
        float s = 0.f;
        #pragma unroll
        for (int i = 0; i < HH / 4; ++i) {
            float4v w = wr[i];
            s += w[0] + w[1] + w[2] + w[3];
        }
        wsum_s[tid] = s;
        bias_s[tid] = bias[tid];
    }

    // ---- A fragments (W): afrag[t][ki] -> A[m=lane&15][h=quad*8+j+32*ki], filter k=t*16+m ----
    short8 afrag[4][2];
    #pragma unroll
    for (int t = 0; t < 4; ++t) {
        const int k = t * 16 + m;
        #pragma unroll
        for (int ki = 0; ki < 2; ++ki) {
            const float4v* wp = (const float4v*)(W + k * HH + quad * 8 + ki * 32);
            float4v w0 = wp[0];
            float4v w1 = wp[1];
            short8 f;
            f[0] = (short)f2bf(w0[0]); f[1] = (short)f2bf(w0[1]);
            f[2] = (short)f2bf(w0[2]); f[3] = (short)f2bf(w0[3]);
            f[4] = (short)f2bf(w1[0]); f[5] = (short)f2bf(w1[1]);
            f[6] = (short)f2bf(w1[2]); f[7] = (short)f2bf(w1[3]);
            afrag[t][ki] = f;
        }
    }

    __syncthreads();

    // ---- Phase B1: window stats: threads 0..127 own 4 consecutive positions each ----
    if (tid < TL / 4) {
        const int p0 = 4 * tid;
        const float4v* xv = (const float4v*)(xs_f + p0);   // 16B aligned
        float s1 = 0.f, s2 = 0.f;
        float4v v0 = xv[0];
        float4v v16 = xv[16];
        #pragma unroll
        for (int i = 0; i < 16; ++i) {
            float4v v = xv[i];
            s1 += v[0] + v[1] + v[2] + v[3];
            s2 += v[0] * v[0] + v[1] * v[1] + v[2] * v[2] + v[3] * v[3];
        }
        float mu4[4], inv4[4];
        #pragma unroll
        for (int i = 0; i < 4; ++i) {
            if (i > 0) {
                float xo = v0[i - 1], xn = v16[i - 1];   // slide window by 1
                s1 += xn - xo;
                s2 += xn * xn - xo * xo;
            }
            float mu  = s1 * (1.f / 64.f);
            float var = (s2 - 64.f * mu * mu) * (1.f / 63.f);
            var = var < 0.f ? 0.f : var;
            mu4[i]  = mu;
            inv4[i] = 1.f / (sqrtf(var) + 1e-6f);
        }
        float4v lo4, hi4;
        lo4[0] = mu4[0]; lo4[1] = inv4[0]; lo4[2] = mu4[1]; lo4[3] = inv4[1];
        hi4[0] = mu4[2]; hi4[1] = inv4[2]; hi4[2] = mu4[3]; hi4[3] = inv4[3];
        *(float4v*)(muinv_s + 8 * tid)     = lo4;   // byte 32*tid -> 16B aligned
        *(float4v*)(muinv_s + 8 * tid + 4) = hi4;
    }

    // ---- Phase B2: build shifted bf16 rows 1..3 from row 0 ----
    // 216 tasks: c = tid/3 in 0..71 (all 72 chunks), s = 1 + tid%3 in 1..3.
    if (tid < 216) {
        const int c = tid / 3;           // 0..71
        const int s = 1 + tid % 3;       // 1..3
        const int i0 = 8 * c + s;        // junk beyond row0[575] lands only at row_s[>=573];
                                         // Phase-C read ceiling is 571 -> never consumed
        short8 w;
        #pragma unroll
        for (int j = 0; j < 8; ++j) w[j] = (short)rep4[i0 + j];
        *(short8*)(rep4 + s * ROW4 + 8 * c) = w;   // 16B aligned
    }
    __syncthreads();
    // xs_f is dead from here; pool becomes the per-wave bounce buffer.

    // ---- Phase C: MFMA + bounce + full-line stores (byte-level identical to R5's body) ----
    // B[k=quad*8+j][n=m] = rep4[m&3][ p0 + (m&12) + quad*8 (+32ki) + j ]  (8B aligned)
    const unsigned short* myrow = rep4 + (m & 3) * ROW4 + (m & 12) + quad * 8;
    float* const bw   = pool + wv * (16 * BSTRIDE);
    float* const outb = out + (size_t)bb * LOUT * KF;

    for (int g = wv; g < TL / 16; g += 4) {
        const int p0 = g * 16;

        // b64 reads, bank-verified conflict-free
        short4v a0 = *(const short4v*)(myrow + p0);
        short4v a1 = *(const short4v*)(myrow + p0 + 4);
        short4v a2 = *(const short4v*)(myrow + p0 + 32);
        short4v a3 = *(const short4v*)(myrow + p0 + 36);
        short8 b0 = __builtin_shufflevector(a0, a1, 0, 1, 2, 3, 4, 5, 6, 7);
        short8 b1 = __builtin_shufflevector(a2, a3, 0, 1, 2, 3, 4, 5, 6, 7);

        float2v mi = *(const float2v*)(muinv_s + 2 * (p0 + m));  // 4-lane broadcast
        const float muv  = mi[0];
        const float invv = mi[1];

        float4v acc[4];
        #pragma unroll
        for (int t = 0; t < 4; ++t) acc[t] = (float4v){0.f, 0.f, 0.f, 0.f};
        #pragma unroll
        for (int t = 0; t < 4; ++t) {
            acc[t] = __builtin_amdgcn_mfma_f32_16x16x32_bf16(afrag[t][0], b0, acc[t], 0, 0, 0);
            acc[t] = __builtin_amdgcn_mfma_f32_16x16x32_bf16(afrag[t][1], b1, acc[t], 0, 0, 0);
        }

        // ---- epilogue: fold layernorm + bias + relu, LDS-bounce to full-line stores ----
        #pragma unroll
        for (int h = 0; h < 2; ++h) {
            #pragma unroll
            for (int e = 0; e < 2; ++e) {
                const int t = 2 * h + e;
                float4v ws = *(const float4v*)(wsum_s + t * 16 + quad * 4);  // broadcast
                float4v bs = *(const float4v*)(bias_s + t * 16 + quad * 4);  // broadcast
                float4v v;
                #pragma unroll
                for (int r = 0; r < 4; ++r) {
                    float vv = (acc[t][r] - muv * ws[r]) * invv + bs[r];
                    v[r] = vv > 0.f ? vv : 0.f;
                }
                *(float4v*)(bw + m * BSTRIDE + e * 16 + quad * 4) = v;
            }
            asm volatile("s_waitcnt lgkmcnt(0)" ::: "memory");   // wave-private bounce
            #pragma unroll
            for (int s = 0; s < 2; ++s) {
                const int pos_in = 8 * s + (lane >> 3);            // 0..15
                const int kh     = 4 * (lane & 7);                 // 0..28
                float4v v = *(const float4v*)(bw + pos_in * BSTRIDE + kh);
                const int pos = block_lo + p0 + pos_in;
                if (pos < LOUT) {
                    // 128B-line chunks, 1KB contiguous per instruction
                    *(float4v*)(outb + (size_t)pos * KF + 32 * h + kh) = v;
                }
            }
            asm volatile("" ::: "memory");   // keep next half's writes after these reads
        }
    }

    // ---- output 1: warmup scalar = 63 ----
    if (tile == 0 && bb == 0 && tid == 0) {
        out[(size_t)16 * LOUT * KF] = 63.0f;
    }
}

extern "C" void kernel_launch(void* const* d_in, const int* in_sizes, int n_in,
                              void* d_out, int out_size, void* d_ws, size_t ws_size,
                              hipStream_t stream) {
    const float* x = (const float*)d_in[0];   // (16, 65536) fp32
    const float* W = (const float*)d_in[1];   // (64, 64) fp32
    const float* b = (const float*)d_in[2];   // (64,) fp32
    float* out = (float*)d_out;               // 16*65473*64 fp32 + 1 (warmup)

    dim3 grid((LOUT + TL - 1) / TL, 16);      // 128 tiles x 16 batches = 2048 blocks
    hankel_kernel<<<grid, 256, 0, stream>>>(x, W, b, out);
}